// Round 1
// baseline (614.906 us; speedup 1.0000x reference)
//
#include <hip/hip_runtime.h>
#include <cstdint>
#include <cstddef>

// FourierAttention: B=4 L=8192 H=16 D=64, Ls=64 -> M=128, BH=64 batch-heads.
// Math: scores[m,n] = sum_l q_l^T G' k_l (complex G', scale folded), logits=|s|,
// A=softmax_n(logits), Out[m,l,:] = sum_n A[m,n] V[n,l,:]  (irfft∘rfft = id).

typedef short bf16x8 __attribute__((ext_vector_type(8)));
typedef float f32x4 __attribute__((ext_vector_type(4)));

__device__ __forceinline__ ushort f2bf(float f) {
    union { float f; uint32_t u; } v; v.f = f;
    uint32_t r = (v.u + 0x7FFFu + ((v.u >> 16) & 1u)) >> 16;
    return (ushort)r;
}

// G'^T tables: GreT[dp*64+d] = Re g(d-dp)/32768, GimT likewise (Im, negated sin sum).
__global__ void k_gmat(float* __restrict__ GreT, float* __restrict__ GimT) {
    const float lam = 1.0f / 32768.0f;
    const float c = 3.14159265358979323846f / 32.0f;   // 2*pi/64
    for (int e = threadIdx.x + blockIdx.x * blockDim.x; e < 4096; e += blockDim.x * gridDim.x) {
        int dp = e >> 6, d = e & 63;
        int delta = d - dp;
        float re = 0.f, im = 0.f;
        for (int k = 0; k <= 32; ++k) {
            int r = ((k * delta) % 64 + 64) % 64;   // reduce angle for fp32 trig accuracy
            float ang = c * (float)r;
            re += cosf(ang);
            im -= sinf(ang);
        }
        GreT[e] = re * lam;
        GimT[e] = im * lam;
    }
}

// Q[b, m*64+l, h, d] fp32 -> Qf[bh][m][l*64+d] bf16
__global__ __launch_bounds__(256) void k_prep_q(const float* __restrict__ Q, ushort* __restrict__ Qf) {
    int blk = blockIdx.x;
    int bh = blk >> 7, m = blk & 127;
    int b = bh >> 4, h = bh & 15;
    const float* qbase = Q + ((size_t)(b * 8192 + m * 64)) * 1024 + h * 64;
    ushort* obase = Qf + ((size_t)bh * 128 + m) * 4096;
    for (int idx = threadIdx.x; idx < 1024; idx += 256) {
        int l = idx >> 4, d4 = (idx & 15) * 4;
        float4 v = *(const float4*)(qbase + (size_t)l * 1024 + d4);
        ushort4 o; o.x = f2bf(v.x); o.y = f2bf(v.y); o.z = f2bf(v.z); o.w = f2bf(v.w);
        *(ushort4*)(obase + idx * 4) = o;
    }
}

// K -> Kre = Gre' k, Kim = Gim' k per (bh, n, l); outputs bf16 [bh][n][l*64+d]
__global__ __launch_bounds__(256) void k_prep_k(const float* __restrict__ K,
                                                const float* __restrict__ GreT,
                                                const float* __restrict__ GimT,
                                                ushort* __restrict__ Kre, ushort* __restrict__ Kim) {
    __shared__ float gre[4096], gim[4096], kT[4096];  // kT[dp][l]
    int blk = blockIdx.x;
    int bh = blk >> 7, n = blk & 127;
    int b = bh >> 4, h = bh & 15;
    int t = threadIdx.x;
    for (int idx = t; idx < 1024; idx += 256) {
        *(float4*)&gre[idx * 4] = *(const float4*)(GreT + idx * 4);
        *(float4*)&gim[idx * 4] = *(const float4*)(GimT + idx * 4);
    }
    int lc = t & 63, dq = t >> 6;
    const float* kbase = K + ((size_t)(b * 8192 + n * 64 + lc)) * 1024 + h * 64;
    #pragma unroll
    for (int r = 0; r < 4; ++r) {
        int d0 = r * 16 + dq * 4;
        float4 v = *(const float4*)(kbase + d0);
        kT[(d0 + 0) * 64 + lc] = v.x; kT[(d0 + 1) * 64 + lc] = v.y;
        kT[(d0 + 2) * 64 + lc] = v.z; kT[(d0 + 3) * 64 + lc] = v.w;
    }
    __syncthreads();
    int d = t & 63, w = t >> 6;
    float re[16], im[16];
    #pragma unroll
    for (int j = 0; j < 16; ++j) { re[j] = 0.f; im[j] = 0.f; }
    for (int dp = 0; dp < 64; ++dp) {
        float gr = gre[dp * 64 + d];
        float gi = gim[dp * 64 + d];
        const float4* kp = (const float4*)&kT[dp * 64 + w * 16];
        #pragma unroll
        for (int q = 0; q < 4; ++q) {
            float4 kv = kp[q];
            re[q * 4 + 0] += gr * kv.x; re[q * 4 + 1] += gr * kv.y;
            re[q * 4 + 2] += gr * kv.z; re[q * 4 + 3] += gr * kv.w;
            im[q * 4 + 0] += gi * kv.x; im[q * 4 + 1] += gi * kv.y;
            im[q * 4 + 2] += gi * kv.z; im[q * 4 + 3] += gi * kv.w;
        }
    }
    ushort* reb = Kre + ((size_t)bh * 128 + n) * 4096;
    ushort* imb = Kim + ((size_t)bh * 128 + n) * 4096;
    #pragma unroll
    for (int j = 0; j < 16; ++j) {
        int off = (w * 16 + j) * 64 + d;
        reb[off] = f2bf(re[j]);
        imb[off] = f2bf(im[j]);
    }
}

// Batched NT GEMM: Sre/Sim[bh][m][n] = sum_j Qf[m][j]*{Kre,Kim}[n][j], K=4096.
// Block: 64m x 64n tile, grid (4 tiles, 64 bh). Wave: 32x32 via 2x2 16x16x32 MFMA.
__global__ __launch_bounds__(256) void k_scores(const ushort* __restrict__ Qf,
                                                const ushort* __restrict__ Kre,
                                                const ushort* __restrict__ Kim,
                                                float* __restrict__ Sre, float* __restrict__ Sim) {
    __shared__ ushort qt[64 * 72], ret[64 * 72], imt[64 * 72];   // +8 bf16 pad per row
    int bh = blockIdx.y;
    int mh = blockIdx.x >> 1, nh = blockIdx.x & 1;
    int m0 = mh * 64, n0 = nh * 64;
    int t = threadIdx.x;
    int lane = t & 63, wave = t >> 6;
    int wm = wave >> 1, wn = wave & 1;
    int row16 = lane & 15, quad = lane >> 4;
    f32x4 accre[2][2] = {};
    f32x4 accim[2][2] = {};
    const ushort* qg = Qf + ((size_t)bh * 128 + m0) * 4096;
    const ushort* rg = Kre + ((size_t)bh * 128 + n0) * 4096;
    const ushort* ig = Kim + ((size_t)bh * 128 + n0) * 4096;
    for (int kt = 0; kt < 64; ++kt) {
        int j0 = kt * 64;
        #pragma unroll
        for (int p = 0; p < 2; ++p) {
            int idx = p * 256 + t;
            int row = idx >> 3, ch = idx & 7;
            size_t go = (size_t)row * 4096 + j0 + ch * 8;
            int lo = row * 72 + ch * 8;
            *(uint4*)&qt[lo]  = *(const uint4*)(qg + go);
            *(uint4*)&ret[lo] = *(const uint4*)(rg + go);
            *(uint4*)&imt[lo] = *(const uint4*)(ig + go);
        }
        __syncthreads();
        #pragma unroll
        for (int kk = 0; kk < 2; ++kk) {
            bf16x8 a[2], br[2], bi[2];
            #pragma unroll
            for (int mt = 0; mt < 2; ++mt)
                a[mt] = *(const bf16x8*)&qt[(wm * 32 + mt * 16 + row16) * 72 + kk * 32 + quad * 8];
            #pragma unroll
            for (int nt = 0; nt < 2; ++nt) {
                br[nt] = *(const bf16x8*)&ret[(wn * 32 + nt * 16 + row16) * 72 + kk * 32 + quad * 8];
                bi[nt] = *(const bf16x8*)&imt[(wn * 32 + nt * 16 + row16) * 72 + kk * 32 + quad * 8];
            }
            #pragma unroll
            for (int mt = 0; mt < 2; ++mt)
                #pragma unroll
                for (int nt = 0; nt < 2; ++nt) {
                    accre[mt][nt] = __builtin_amdgcn_mfma_f32_16x16x32_bf16(a[mt], br[nt], accre[mt][nt], 0, 0, 0);
                    accim[mt][nt] = __builtin_amdgcn_mfma_f32_16x16x32_bf16(a[mt], bi[nt], accim[mt][nt], 0, 0, 0);
                }
        }
        __syncthreads();
    }
    float* sre = Sre + (size_t)bh * 16384;
    float* sim = Sim + (size_t)bh * 16384;
    #pragma unroll
    for (int mt = 0; mt < 2; ++mt)
        #pragma unroll
        for (int nt = 0; nt < 2; ++nt)
            #pragma unroll
            for (int i = 0; i < 4; ++i) {
                int r = m0 + wm * 32 + mt * 16 + quad * 4 + i;
                int c = n0 + wn * 32 + nt * 16 + row16;
                sre[r * 128 + c] = accre[mt][nt][i];
                sim[r * 128 + c] = accim[mt][nt][i];
            }
}

// logits = sqrt(re^2+im^2); softmax over n (128); A bf16
__global__ __launch_bounds__(128) void k_softmax(const float* __restrict__ Sre,
                                                 const float* __restrict__ Sim,
                                                 ushort* __restrict__ A) {
    __shared__ float redmax[2], redsum[2];
    int row = blockIdx.x;   // bh*128 + m
    int t = threadIdx.x;
    size_t off = (size_t)row * 128 + t;
    float re = Sre[off], im = Sim[off];
    float lg = sqrtf(re * re + im * im);
    float v = lg;
    for (int o = 32; o > 0; o >>= 1) v = fmaxf(v, __shfl_xor(v, o));
    if ((t & 63) == 0) redmax[t >> 6] = v;
    __syncthreads();
    float mx = fmaxf(redmax[0], redmax[1]);
    float e = expf(lg - mx);
    float s = e;
    for (int o = 32; o > 0; o >>= 1) s += __shfl_xor(s, o);
    if ((t & 63) == 0) redsum[t >> 6] = s;
    __syncthreads();
    float tot = redsum[0] + redsum[1];
    A[off] = f2bf(e / tot);
}

// V[b, n*64+l, h, d] -> Vt[bh][l*64+d][n] bf16 (64x64 LDS tile transpose per (bh,l,nh))
__global__ __launch_bounds__(256) void k_vt(const float* __restrict__ V, ushort* __restrict__ Vt) {
    __shared__ float tile[64 * 68];
    int l = blockIdx.x, nh = blockIdx.y, bh = blockIdx.z;
    int b = bh >> 4, h = bh & 15;
    int t = threadIdx.x;
    int n = t & 63, dq = t >> 6;
    const float* vbase = V + ((size_t)(b * 8192 + (nh * 64 + n) * 64 + l)) * 1024 + h * 64;
    #pragma unroll
    for (int r = 0; r < 4; ++r) {
        int d0 = r * 16 + dq * 4;
        float4 v = *(const float4*)(vbase + d0);
        tile[(d0 + 0) * 68 + n] = v.x; tile[(d0 + 1) * 68 + n] = v.y;
        tile[(d0 + 2) * 68 + n] = v.z; tile[(d0 + 3) * 68 + n] = v.w;
    }
    __syncthreads();
    int d = t >> 2, cq = t & 3;
    __align__(16) ushort u[16];
    #pragma unroll
    for (int i = 0; i < 16; ++i) u[i] = f2bf(tile[d * 68 + cq * 16 + i]);
    ushort* ob = Vt + ((size_t)bh * 4096 + l * 64 + d) * 128 + nh * 64 + cq * 16;
    *(uint4*)(ob) = *(uint4*)&u[0];
    *(uint4*)(ob + 8) = *(uint4*)&u[8];
}

// Out[m, j=(l,d)] = sum_n A[m][n] * Vt[j][n]; NT GEMM, K=128, per (bh, 64-wide j tile)
__global__ __launch_bounds__(256) void k_mix(const ushort* __restrict__ A,
                                             const ushort* __restrict__ Vt,
                                             float* __restrict__ Out) {
    __shared__ ushort At[128 * 136], Vtl[64 * 136];
    int jt = blockIdx.x, bh = blockIdx.y;
    int b = bh >> 4, h = bh & 15;
    int j0 = jt * 64;
    int t = threadIdx.x;
    int lane = t & 63, wave = t >> 6;
    int row16 = lane & 15, quad = lane >> 4;
    const ushort* ag = A + (size_t)bh * 16384;
    const ushort* vg = Vt + ((size_t)bh * 4096 + j0) * 128;
    #pragma unroll
    for (int p = 0; p < 8; ++p) {
        int idx = p * 256 + t;
        int row = idx >> 4, ch = idx & 15;
        *(uint4*)&At[row * 136 + ch * 8] = *(const uint4*)(ag + row * 128 + ch * 8);
    }
    #pragma unroll
    for (int p = 0; p < 4; ++p) {
        int idx = p * 256 + t;
        int row = idx >> 4, ch = idx & 15;
        *(uint4*)&Vtl[row * 136 + ch * 8] = *(const uint4*)(vg + (size_t)row * 128 + ch * 8);
    }
    __syncthreads();
    f32x4 acc[2][4] = {};
    #pragma unroll
    for (int kk = 0; kk < 4; ++kk) {
        bf16x8 a[2], bv[4];
        #pragma unroll
        for (int mt = 0; mt < 2; ++mt)
            a[mt] = *(const bf16x8*)&At[(wave * 32 + mt * 16 + row16) * 136 + kk * 32 + quad * 8];
        #pragma unroll
        for (int j2 = 0; j2 < 4; ++j2)
            bv[j2] = *(const bf16x8*)&Vtl[(j2 * 16 + row16) * 136 + kk * 32 + quad * 8];
        #pragma unroll
        for (int mt = 0; mt < 2; ++mt)
            #pragma unroll
            for (int j2 = 0; j2 < 4; ++j2)
                acc[mt][j2] = __builtin_amdgcn_mfma_f32_16x16x32_bf16(a[mt], bv[j2], acc[mt][j2], 0, 0, 0);
    }
    #pragma unroll
    for (int mt = 0; mt < 2; ++mt)
        #pragma unroll
        for (int j2 = 0; j2 < 4; ++j2)
            #pragma unroll
            for (int i = 0; i < 4; ++i) {
                int m = wave * 32 + mt * 16 + quad * 4 + i;
                int j = j0 + j2 * 16 + row16;
                int ll = j >> 6, d = j & 63;
                Out[((size_t)(b * 8192 + m * 64 + ll)) * 1024 + h * 64 + d] = acc[mt][j2][i];
            }
}

extern "C" void kernel_launch(void* const* d_in, const int* in_sizes, int n_in,
                              void* d_out, int out_size, void* d_ws, size_t ws_size,
                              hipStream_t stream) {
    const float* Q = (const float*)d_in[0];
    const float* K = (const float*)d_in[1];
    const float* V = (const float*)d_in[2];
    float* Out = (float*)d_out;
    char* ws = (char*)d_ws;
    // ws layout (total ~202 MiB):
    float* GreT = (float*)ws;                                   // 16 KB
    float* GimT = (float*)(ws + 16384);                         // 16 KB
    float* Sre  = (float*)(ws + 32768);                         // 4 MB
    float* Sim  = (float*)(ws + 32768 + 4194304);               // 4 MB
    ushort* A   = (ushort*)(ws + 32768 + 2 * 4194304);          // 2 MB
    ushort* Qf  = (ushort*)(ws + 32768 + 2 * 4194304 + 2097152);// 64 MB
    ushort* Kre = Qf + 33554432;                                // 64 MB
    ushort* Kim = Kre + 33554432;                               // 64 MB
    ushort* Vt  = Qf;  // alias: Qf is dead after k_scores

    k_gmat<<<16, 256, 0, stream>>>(GreT, GimT);
    k_prep_q<<<8192, 256, 0, stream>>>(Q, Qf);
    k_prep_k<<<8192, 256, 0, stream>>>(K, GreT, GimT, Kre, Kim);
    k_scores<<<dim3(4, 64), 256, 0, stream>>>(Qf, Kre, Kim, Sre, Sim);
    k_softmax<<<8192, 128, 0, stream>>>(Sre, Sim, A);
    k_vt<<<dim3(64, 2, 64), 256, 0, stream>>>(V, Vt);
    k_mix<<<dim3(64, 64), 256, 0, stream>>>(A, Vt, Out);
}